// Round 1
// baseline (5799.681 us; speedup 1.0000x reference)
//
#include <hip/hip_runtime.h>
#include <math.h>

// ---------------- problem constants ----------------
#define BB 2
#define TT 1024
#define DMODEL 2048
#define NH 32
#define DKH 48
#define DVH 96
#define KD 1536
#define VD 3072
#define INTER 5632
#define BT (BB*TT)

__device__ __forceinline__ float siluf(float x) { return x / (1.f + __expf(-x)); }

// ---------------- rmsnorm (row of 2048) ----------------
__global__ __launch_bounds__(256) void rmsnorm_kernel(
    const float* __restrict__ x, const float* __restrict__ w, float* __restrict__ out)
{
    int m = blockIdx.x;
    int tid = threadIdx.x;
    const float4* xr = (const float4*)(x + (size_t)m * DMODEL);
    float4 a = xr[tid];
    float4 b = xr[tid + 256];
    float ss = a.x*a.x + a.y*a.y + a.z*a.z + a.w*a.w
             + b.x*b.x + b.y*b.y + b.z*b.z + b.w*b.w;
    #pragma unroll
    for (int off = 32; off; off >>= 1) ss += __shfl_xor(ss, off);
    __shared__ float wsum[4];
    if ((tid & 63) == 0) wsum[tid >> 6] = ss;
    __syncthreads();
    float tot = wsum[0] + wsum[1] + wsum[2] + wsum[3];
    float rn = rsqrtf(tot * (1.f / DMODEL) + 1e-5f);
    const float4* wr = (const float4*)w;
    float4 w0 = wr[tid], w1 = wr[tid + 256];
    float4 o0, o1;
    o0.x = a.x*rn*w0.x; o0.y = a.y*rn*w0.y; o0.z = a.z*rn*w0.z; o0.w = a.w*rn*w0.w;
    o1.x = b.x*rn*w1.x; o1.y = b.y*rn*w1.y; o1.z = b.z*rn*w1.z; o1.w = b.w*rn*w1.w;
    float4* orow = (float4*)(out + (size_t)m * DMODEL);
    orow[tid] = o0; orow[tid + 256] = o1;
}

// ---------------- fp32 GEMM 128x128 tile, BK=8, 8x8/thread ----------------
// MODE 0: C = A@B ; MODE 1: C = A@B + X ; MODE 2: C = silu(X) * (A@B)
template <int MODE>
__global__ __launch_bounds__(256) void gemm128(
    const float* __restrict__ A, const float* __restrict__ Bm,
    float* __restrict__ C, const float* __restrict__ X,
    int M, int N, int K)
{
    __shared__ __align__(16) float As[8][128];
    __shared__ __align__(16) float Bs[8][128];
    int tid = threadIdx.x;
    int bx = blockIdx.x, by = blockIdx.y;
    int tx = tid & 15, ty = tid >> 4;
    int row_a = tid & 127, kha = (tid >> 7) << 2;
    int row_b = tid >> 5, col_b = (tid & 31) << 2;
    const float* Ap = A + (size_t)(by * 128 + row_a) * K + kha;
    const float* Bp = Bm + (size_t)row_b * N + bx * 128 + col_b;
    float acc[8][8];
    #pragma unroll
    for (int i = 0; i < 8; i++)
        #pragma unroll
        for (int j = 0; j < 8; j++) acc[i][j] = 0.f;

    for (int k0 = 0; k0 < K; k0 += 8) {
        float4 av = *(const float4*)(Ap + k0);
        float4 bv = *(const float4*)(Bp + (size_t)k0 * N);
        __syncthreads();
        As[kha + 0][row_a] = av.x;
        As[kha + 1][row_a] = av.y;
        As[kha + 2][row_a] = av.z;
        As[kha + 3][row_a] = av.w;
        *(float4*)&Bs[row_b][col_b] = bv;
        __syncthreads();
        #pragma unroll
        for (int kk = 0; kk < 8; kk++) {
            float a[8], b[8];
            *(float4*)(a)     = *(const float4*)&As[kk][ty * 8];
            *(float4*)(a + 4) = *(const float4*)&As[kk][ty * 8 + 4];
            *(float4*)(b)     = *(const float4*)&Bs[kk][tx * 8];
            *(float4*)(b + 4) = *(const float4*)&Bs[kk][tx * 8 + 4];
            #pragma unroll
            for (int i = 0; i < 8; i++)
                #pragma unroll
                for (int j = 0; j < 8; j++)
                    acc[i][j] = fmaf(a[i], b[j], acc[i][j]);
        }
    }

    int r0 = by * 128 + ty * 8;
    int c0 = bx * 128 + tx * 8;
    #pragma unroll
    for (int i = 0; i < 8; i++) {
        float* crow = C + (size_t)(r0 + i) * N + c0;
        const float* xrow = (MODE != 0) ? (X + (size_t)(r0 + i) * N + c0) : nullptr;
        #pragma unroll
        for (int j = 0; j < 8; j += 4) {
            float4 val;
            val.x = acc[i][j]; val.y = acc[i][j+1]; val.z = acc[i][j+2]; val.w = acc[i][j+3];
            if (MODE == 1) {
                float4 xv = *(const float4*)(xrow + j);
                val.x += xv.x; val.y += xv.y; val.z += xv.z; val.w += xv.w;
            } else if (MODE == 2) {
                float4 xv = *(const float4*)(xrow + j);
                val.x *= siluf(xv.x); val.y *= siluf(xv.y);
                val.z *= siluf(xv.z); val.w *= siluf(xv.w);
            }
            *(float4*)(crow + j) = val;
        }
    }
}

// ---------------- small projections + gating activations (Wa, Wb -> g, beta) ----------------
__global__ __launch_bounds__(256) void proj_gb_kernel(
    const float* __restrict__ h, const float* __restrict__ Wa, const float* __restrict__ Wb,
    const float* __restrict__ dt_bias, const float* __restrict__ A_log,
    float* __restrict__ g, float* __restrict__ beta)
{
    int m = blockIdx.x, tid = threadIdx.x;
    __shared__ __align__(16) float hs[DMODEL];
    const float4* hr = (const float4*)(h + (size_t)m * DMODEL);
    ((float4*)hs)[tid] = hr[tid];
    ((float4*)hs)[tid + 256] = hr[tid + 256];
    __syncthreads();
    int out = tid >> 2;   // 0..63: 0..31 -> Wa, 32..63 -> Wb
    int part = tid & 3;
    int j = out & 31;
    const float* W = (out < 32) ? Wa : Wb;
    float s = 0.f;
    for (int kk = part; kk < DMODEL; kk += 4)
        s += hs[kk] * W[(size_t)kk * NH + j];
    s += __shfl_xor(s, 1);
    s += __shfl_xor(s, 2);
    if (part == 0) {
        if (out < 32) {
            float xx = s + dt_bias[j];
            float sp = (xx > 20.f) ? xx : log1pf(expf(xx));
            g[(size_t)m * NH + j] = -expf(A_log[j]) * sp;
        } else {
            beta[(size_t)m * NH + j] = 1.f / (1.f + expf(-s));
        }
    }
}

// ---------------- causal depthwise conv(K=4) + silu + per-head l2norm (q/k) ----------------
__global__ __launch_bounds__(256) void conv_qk_kernel(
    const float* __restrict__ pre, const float* __restrict__ w, float* __restrict__ out)
{
    int m = blockIdx.x;
    int b = m >> 10, t = m & 1023;
    int tid = threadIdx.x;
    int c0 = tid * 6;                 // 6 channels/thread, 8 threads per head (48 ch)
    float o[6]; float ss = 0.f;
    #pragma unroll
    for (int jj = 0; jj < 6; jj++) {
        int c = c0 + jj;
        float acc = 0.f;
        #pragma unroll
        for (int kk = 0; kk < 4; kk++) {
            int tt = t - 3 + kk;
            if (tt >= 0)
                acc += pre[((size_t)(b * TT + tt)) * KD + c] * w[c * 4 + kk];
        }
        float s = siluf(acc);
        o[jj] = s; ss += s * s;
    }
    ss += __shfl_xor(ss, 1); ss += __shfl_xor(ss, 2); ss += __shfl_xor(ss, 4);
    float rn = rsqrtf(ss + 1e-6f);
    float* orow = out + (size_t)m * KD + c0;
    #pragma unroll
    for (int jj = 0; jj < 6; jj++) orow[jj] = o[jj] * rn;
}

// ---------------- causal depthwise conv(K=4) + silu (v) ----------------
__global__ __launch_bounds__(256) void conv_v_kernel(
    const float* __restrict__ pre, const float* __restrict__ w, float* __restrict__ out)
{
    int m = blockIdx.x;
    int b = m >> 10, t = m & 1023;
    int tid = threadIdx.x;
    int c0 = tid * 12;
    float* orow = out + (size_t)m * VD + c0;
    #pragma unroll
    for (int jj = 0; jj < 12; jj++) {
        int c = c0 + jj;
        float acc = 0.f;
        #pragma unroll
        for (int kk = 0; kk < 4; kk++) {
            int tt = t - 3 + kk;
            if (tt >= 0)
                acc += pre[((size_t)(b * TT + tt)) * VD + c] * w[c * 4 + kk];
        }
        orow[jj] = siluf(acc);
    }
}

// ---------------- gated delta rule scan ----------------
// one block per (b,h); thread j owns column j of the 48x96 state (in registers)
#define SCH 32
__global__ __launch_bounds__(96) void scan_kernel(
    const float* __restrict__ q, const float* __restrict__ k, const float* __restrict__ v,
    const float* __restrict__ g, const float* __restrict__ beta, float* __restrict__ o)
{
    int bh = blockIdx.x;
    int b = bh >> 5, h = bh & 31;
    int tid = threadIdx.x;      // 0..95 = DV column
    __shared__ __align__(16) float ks[SCH][DKH];
    __shared__ __align__(16) float qs[SCH][DKH];
    __shared__ __align__(16) float vs[SCH][DVH];
    __shared__ float gs[SCH], bs[SCH];
    float S[DKH];
    #pragma unroll
    for (int r = 0; r < DKH; r++) S[r] = 0.f;
    const float scale = 0.14433756729740643f;   // 48^-0.5

    for (int t0 = 0; t0 < TT; t0 += SCH) {
        __syncthreads();
        for (int idx = tid; idx < SCH * DKH; idx += 96) {
            int ttc = idx / DKH, i = idx % DKH;
            size_t goff = ((size_t)(b * TT + t0 + ttc)) * KD + h * DKH + i;
            ks[ttc][i] = k[goff];
            qs[ttc][i] = q[goff];
        }
        for (int idx = tid; idx < SCH * DVH; idx += 96) {
            int ttc = idx / DVH, i = idx % DVH;
            vs[ttc][i] = v[((size_t)(b * TT + t0 + ttc)) * VD + h * DVH + i];
        }
        if (tid < SCH) {
            gs[tid] = g[(size_t)(b * TT + t0 + tid) * NH + h];
            bs[tid] = beta[(size_t)(b * TT + t0 + tid) * NH + h];
        }
        __syncthreads();

        for (int tc = 0; tc < SCH; tc++) {
            float eg = __expf(gs[tc]);
            float bt = bs[tc];
            float vt = vs[tc][tid];
            const float4* kv = (const float4*)&ks[tc][0];
            const float4* qv = (const float4*)&qs[tc][0];
            float4 kr[12];
            float m0 = 0.f, m1 = 0.f, m2 = 0.f, m3 = 0.f;
            #pragma unroll
            for (int r4 = 0; r4 < 12; r4++) {
                float4 kk4 = kv[r4];
                kr[r4] = kk4;
                S[4*r4+0] *= eg; m0 = fmaf(kk4.x, S[4*r4+0], m0);
                S[4*r4+1] *= eg; m1 = fmaf(kk4.y, S[4*r4+1], m1);
                S[4*r4+2] *= eg; m2 = fmaf(kk4.z, S[4*r4+2], m2);
                S[4*r4+3] *= eg; m3 = fmaf(kk4.w, S[4*r4+3], m3);
            }
            float delta = (vt - ((m0 + m1) + (m2 + m3))) * bt;
            float o0 = 0.f, o1 = 0.f, o2 = 0.f, o3 = 0.f;
            #pragma unroll
            for (int r4 = 0; r4 < 12; r4++) {
                float4 kk4 = kr[r4];
                float4 qq4 = qv[r4];
                S[4*r4+0] = fmaf(kk4.x, delta, S[4*r4+0]); o0 = fmaf(qq4.x, S[4*r4+0], o0);
                S[4*r4+1] = fmaf(kk4.y, delta, S[4*r4+1]); o1 = fmaf(qq4.y, S[4*r4+1], o1);
                S[4*r4+2] = fmaf(kk4.z, delta, S[4*r4+2]); o2 = fmaf(qq4.z, S[4*r4+2], o2);
                S[4*r4+3] = fmaf(kk4.w, delta, S[4*r4+3]); o3 = fmaf(qq4.w, S[4*r4+3], o3);
            }
            o[((size_t)(b * TT + t0 + tc)) * VD + h * DVH + tid] =
                ((o0 + o1) + (o2 + o3)) * scale;
        }
    }
}

// ---------------- gated per-head RMSNorm * silu(gate) ----------------
__global__ __launch_bounds__(256) void gatednorm_kernel(
    const float* __restrict__ oraw, const float* __restrict__ gate,
    const float* __restrict__ gw, float* __restrict__ out)
{
    int m = blockIdx.x, tid = threadIdx.x;
    int c0 = tid * 12;                 // 8 threads per head (96 ch)
    float o[12]; float ss = 0.f;
    const float* orow = oraw + (size_t)m * VD + c0;
    #pragma unroll
    for (int jj = 0; jj < 12; jj++) { float v_ = orow[jj]; o[jj] = v_; ss += v_ * v_; }
    ss += __shfl_xor(ss, 1); ss += __shfl_xor(ss, 2); ss += __shfl_xor(ss, 4);
    float rn = rsqrtf(ss * (1.f / 96.f) + 1e-5f);
    const float* grow = gate + (size_t)m * VD + c0;
    float* outr = out + (size_t)m * VD + c0;
    int cw0 = c0 % 96;
    #pragma unroll
    for (int jj = 0; jj < 12; jj++) {
        float gt = grow[jj];
        outr[jj] = o[jj] * rn * gw[cw0 + jj] * siluf(gt);
    }
}

// ---------------- host launch ----------------
extern "C" void kernel_launch(void* const* d_in, const int* in_sizes, int n_in,
                              void* d_out, int out_size, void* d_ws, size_t ws_size,
                              hipStream_t stream)
{
    const float* x        = (const float*)d_in[0];
    const float* rms1_w   = (const float*)d_in[1];
    const float* rms2_w   = (const float*)d_in[2];
    const float* Wq       = (const float*)d_in[3];
    const float* Wk       = (const float*)d_in[4];
    const float* Wv       = (const float*)d_in[5];
    const float* Wa       = (const float*)d_in[6];
    const float* Wb       = (const float*)d_in[7];
    const float* Wg       = (const float*)d_in[8];
    const float* dt_bias  = (const float*)d_in[9];
    const float* A_log    = (const float*)d_in[10];
    const float* conv_q_w = (const float*)d_in[11];
    const float* conv_k_w = (const float*)d_in[12];
    const float* conv_v_w = (const float*)d_in[13];
    const float* gnorm_w  = (const float*)d_in[14];
    const float* Wo       = (const float*)d_in[15];
    const float* W1       = (const float*)d_in[16];
    const float* W3       = (const float*)d_in[17];
    const float* W2       = (const float*)d_in[18];

    float* ws = (float*)d_ws;
    const size_t M1 = 1u << 20;
    // arena (aliasing is lifetime-checked; 46M floats = 184 MB total)
    float* h    = ws;                    // [0,4M)
    float* qpre = ws + 4 * M1;           // [4M,7M)
    float* kpre = ws + 7 * M1;           // [7M,10M)
    float* vpre = ws + 10 * M1;          // [10M,16M)
    float* gate = ws + 16 * M1;          // [16M,22M)
    float* gbuf = ws + 22 * M1;          // 64K
    float* bbuf = ws + 22 * M1 + 65536;  // 64K
    float* qb   = ws + 23 * M1;          // [23M,26M)
    float* kb   = ws + 26 * M1;          // [26M,29M)
    float* vb   = ws + 29 * M1;          // [29M,35M)
    float* oraw = ws + 4 * M1;           // alias qpre+kpre (dead after convs)
    float* o2   = ws + 10 * M1;          // alias vpre (dead after conv_v)
    float* h2   = ws + 16 * M1;          // alias gate (dead after gatednorm)
    float* ff   = ws + 20 * M1;          // alias gate tail + gbuf/bbuf + qb head (dead)
    float* t1   = ws + 24 * M1;          // [24M,35M) alias qb tail/kb/vb (dead after scan)
    float* u    = ws + 35 * M1;          // [35M,46M)
    (void)ws_size; (void)n_in; (void)in_sizes; (void)out_size;

    // 1. h = rmsnorm(x, rms1_w)
    rmsnorm_kernel<<<BT, 256, 0, stream>>>(x, rms1_w, h);
    // 2. projections
    gemm128<0><<<dim3(KD / 128, BT / 128), 256, 0, stream>>>(h, Wq, qpre, nullptr, BT, KD, DMODEL);
    gemm128<0><<<dim3(KD / 128, BT / 128), 256, 0, stream>>>(h, Wk, kpre, nullptr, BT, KD, DMODEL);
    gemm128<0><<<dim3(VD / 128, BT / 128), 256, 0, stream>>>(h, Wv, vpre, nullptr, BT, VD, DMODEL);
    gemm128<0><<<dim3(VD / 128, BT / 128), 256, 0, stream>>>(h, Wg, gate, nullptr, BT, VD, DMODEL);
    proj_gb_kernel<<<BT, 256, 0, stream>>>(h, Wa, Wb, dt_bias, A_log, gbuf, bbuf);
    // 3. convs (+silu, +l2norm for q/k)
    conv_qk_kernel<<<BT, 256, 0, stream>>>(qpre, conv_q_w, qb);
    conv_qk_kernel<<<BT, 256, 0, stream>>>(kpre, conv_k_w, kb);
    conv_v_kernel<<<BT, 256, 0, stream>>>(vpre, conv_v_w, vb);
    // 4. gated delta rule scan
    scan_kernel<<<BB * NH, 96, 0, stream>>>(qb, kb, vb, gbuf, bbuf, oraw);
    // 5. gated per-head rmsnorm * silu(gate)
    gatednorm_kernel<<<BT, 256, 0, stream>>>(oraw, gate, gnorm_w, o2);
    // 6. h2 = x + o2 @ Wo
    gemm128<1><<<dim3(DMODEL / 128, BT / 128), 256, 0, stream>>>(o2, Wo, h2, x, BT, DMODEL, VD);
    // 7. MLP
    rmsnorm_kernel<<<BT, 256, 0, stream>>>(h2, rms2_w, ff);
    gemm128<0><<<dim3(INTER / 128, BT / 128), 256, 0, stream>>>(ff, W1, t1, nullptr, BT, INTER, DMODEL);
    gemm128<2><<<dim3(INTER / 128, BT / 128), 256, 0, stream>>>(ff, W3, u, t1, BT, INTER, DMODEL);
    gemm128<1><<<dim3(DMODEL / 128, BT / 128), 256, 0, stream>>>(u, W2, (float*)d_out, h2, BT, DMODEL, INTER);
}

// Round 4
// 2182.853 us; speedup vs baseline: 2.6569x; 2.6569x over previous
//
#include <hip/hip_runtime.h>
#include <math.h>

// ---------------- problem constants ----------------
#define BB 2
#define TT 1024
#define DMODEL 2048
#define NH 32
#define DKH 48
#define DVH 96
#define KD 1536
#define VD 3072
#define INTER 5632
#define BT (BB*TT)

typedef unsigned short u16;
typedef __attribute__((ext_vector_type(8))) short bf16x8;
typedef __attribute__((ext_vector_type(4))) float f32x4;

__device__ __forceinline__ float siluf(float x) { return x / (1.f + __expf(-x)); }

__device__ __forceinline__ float bf2f(u16 u) {
    union { unsigned int i; float f; } v; v.i = ((unsigned int)u) << 16; return v.f;
}
__device__ __forceinline__ u16 f2bf(float f) {
    union { float f; unsigned int i; } v; v.f = f;
    unsigned int r = v.i + 0x7FFFu + ((v.i >> 16) & 1u);   // RNE
    return (u16)(r >> 16);
}

__device__ __forceinline__ void async_copy16(const void* g, void* l) {
    __builtin_amdgcn_global_load_lds(
        (const __attribute__((address_space(1))) void*)g,
        (__attribute__((address_space(3))) void*)l, 16, 0, 0);
}

// ---------------- rmsnorm (row of 2048) -> bf16 ----------------
__global__ __launch_bounds__(256) void rmsnorm_kernel(
    const float* __restrict__ x, const float* __restrict__ w, u16* __restrict__ out)
{
    int m = blockIdx.x;
    int tid = threadIdx.x;
    const float4* xr = (const float4*)(x + (size_t)m * DMODEL);
    float4 a = xr[tid];
    float4 b = xr[tid + 256];
    float ss = a.x*a.x + a.y*a.y + a.z*a.z + a.w*a.w
             + b.x*b.x + b.y*b.y + b.z*b.z + b.w*b.w;
    #pragma unroll
    for (int off = 32; off; off >>= 1) ss += __shfl_xor(ss, off);
    __shared__ float wsum[4];
    if ((tid & 63) == 0) wsum[tid >> 6] = ss;
    __syncthreads();
    float tot = wsum[0] + wsum[1] + wsum[2] + wsum[3];
    float rn = rsqrtf(tot * (1.f / DMODEL) + 1e-5f);
    const float4* wr = (const float4*)w;
    float4 w0 = wr[tid], w1 = wr[tid + 256];
    ushort4 p0, p1;
    p0.x = f2bf(a.x*rn*w0.x); p0.y = f2bf(a.y*rn*w0.y);
    p0.z = f2bf(a.z*rn*w0.z); p0.w = f2bf(a.w*rn*w0.w);
    p1.x = f2bf(b.x*rn*w1.x); p1.y = f2bf(b.y*rn*w1.y);
    p1.z = f2bf(b.z*rn*w1.z); p1.w = f2bf(b.w*rn*w1.w);
    ushort4* orow = (ushort4*)(out + (size_t)m * DMODEL);
    orow[tid] = p0; orow[tid + 256] = p1;
}

// ---------------- weight transpose + cast: in[K][N] f32 -> out[N][K] bf16 ----------------
__global__ __launch_bounds__(256) void transpose_cast(
    const float* __restrict__ in, u16* __restrict__ out, int K, int N)
{
    __shared__ float t[32][33];
    int bx = blockIdx.x;            // over N/32
    int by = blockIdx.y;            // over K/32
    int tx = threadIdx.x & 31, ty = threadIdx.x >> 5;   // ty 0..7
    #pragma unroll
    for (int r = ty; r < 32; r += 8)
        t[r][tx] = in[(size_t)(by * 32 + r) * N + bx * 32 + tx];
    __syncthreads();
    #pragma unroll
    for (int r = ty; r < 32; r += 8)
        out[(size_t)(bx * 32 + r) * K + by * 32 + tx] = f2bf(t[tx][r]);
}

// ---------------- bf16 MFMA GEMM: C[M][N] = A[M][K] @ Bt[N][K]^T  (m97 structure) ----
// MODE 0: C=f32 acc ; MODE 1: C=f32 acc + X ; MODE 2: C=bf16 silu(X)*acc
template <int MODE>
__global__ __launch_bounds__(256) void gemm_bf16(
    const u16* __restrict__ A, const u16* __restrict__ Bt,
    void* __restrict__ Cv, const float* __restrict__ X,
    int M, int N, int K)
{
    __shared__ __align__(16) u16 As[128 * 32];
    __shared__ __align__(16) u16 Bs[128 * 32];
    int tid = threadIdx.x;
    int wave = tid >> 6, lane = tid & 63;
    int wr = wave >> 1, wc = wave & 1;
    int brow = blockIdx.y * 128, bcol = blockIdx.x * 128;
    int lr = lane & 15, lg = lane >> 4;

    f32x4 acc[4][4] = {};

    int ch0 = wave * 128 + lane;        // staging chunk, call 0
    int ra0 = ch0 >> 2, pa0 = (ch0 & 3) * 8;
    int ch1 = ch0 + 64;                 // call 1
    int ra1 = ch1 >> 2, pa1 = (ch1 & 3) * 8;

    const u16* gA0 = A  + (size_t)(brow + ra0) * K + pa0;
    const u16* gA1 = A  + (size_t)(brow + ra1) * K + pa1;
    const u16* gB0 = Bt + (size_t)(bcol + ra0) * K + pa0;
    const u16* gB1 = Bt + (size_t)(bcol + ra1) * K + pa1;

    for (int kt = 0; kt < K; kt += 32) {
        __syncthreads();                          // prior reads done before overwrite
        async_copy16(gA0 + kt, &As[ch0 * 8]);
        async_copy16(gA1 + kt, &As[ch1 * 8]);
        async_copy16(gB0 + kt, &Bs[ch0 * 8]);
        async_copy16(gB1 + kt, &Bs[ch1 * 8]);
        __syncthreads();                          // compiler drains vmcnt before barrier

        bf16x8 aF[4], bF[4];
        #pragma unroll
        for (int m = 0; m < 4; m++)
            aF[m] = *(const bf16x8*)&As[(wr * 64 + m * 16 + lr) * 32 + lg * 8];
        #pragma unroll
        for (int n = 0; n < 4; n++)
            bF[n] = *(const bf16x8*)&Bs[(wc * 64 + n * 16 + lr) * 32 + lg * 8];
        #pragma unroll
        for (int m = 0; m < 4; m++)
            #pragma unroll
            for (int n = 0; n < 4; n++)
                acc[m][n] = __builtin_amdgcn_mfma_f32_16x16x32_bf16(
                    aF[m], bF[n], acc[m][n], 0, 0, 0);
    }

    // epilogue: C/D layout col=lane&15, row=(lane>>4)*4+reg  [m89-verified]
    int r0 = brow + wr * 64 + lg * 4;
    int c0 = bcol + wc * 64 + lr;
    #pragma unroll
    for (int m = 0; m < 4; m++) {
        #pragma unroll
        for (int n = 0; n < 4; n++) {
            #pragma unroll
            for (int r = 0; r < 4; r++) {
                size_t idx = (size_t)(r0 + m * 16 + r) * N + (c0 + n * 16);
                float v = acc[m][n][r];
                if (MODE == 0) {
                    ((float*)Cv)[idx] = v;
                } else if (MODE == 1) {
                    ((float*)Cv)[idx] = v + X[idx];
                } else {
                    ((u16*)Cv)[idx] = f2bf(v * siluf(X[idx]));
                }
            }
        }
    }
}

// ---------------- small projections + gating activations (Wa, Wb -> g, beta) --------
__global__ __launch_bounds__(256) void proj_gb_kernel(
    const u16* __restrict__ h, const float* __restrict__ Wa, const float* __restrict__ Wb,
    const float* __restrict__ dt_bias, const float* __restrict__ A_log,
    float* __restrict__ g, float* __restrict__ beta)
{
    int m = blockIdx.x, tid = threadIdx.x;
    __shared__ __align__(16) float hs[DMODEL];
    const uint4* hr = (const uint4*)(h + (size_t)m * DMODEL);
    uint4 hv = hr[tid];
    int base = tid * 8;
    hs[base + 0] = bf2f((u16)(hv.x & 0xffff)); hs[base + 1] = bf2f((u16)(hv.x >> 16));
    hs[base + 2] = bf2f((u16)(hv.y & 0xffff)); hs[base + 3] = bf2f((u16)(hv.y >> 16));
    hs[base + 4] = bf2f((u16)(hv.z & 0xffff)); hs[base + 5] = bf2f((u16)(hv.z >> 16));
    hs[base + 6] = bf2f((u16)(hv.w & 0xffff)); hs[base + 7] = bf2f((u16)(hv.w >> 16));
    __syncthreads();
    int out = tid >> 2;   // 0..63: 0..31 -> Wa, 32..63 -> Wb
    int part = tid & 3;
    int j = out & 31;
    const float* W = (out < 32) ? Wa : Wb;
    float s = 0.f;
    for (int kk = part; kk < DMODEL; kk += 4)
        s += hs[kk] * W[(size_t)kk * NH + j];
    s += __shfl_xor(s, 1);
    s += __shfl_xor(s, 2);
    if (part == 0) {
        if (out < 32) {
            float xx = s + dt_bias[j];
            float sp = (xx > 20.f) ? xx : log1pf(expf(xx));
            g[(size_t)m * NH + j] = -expf(A_log[j]) * sp;
        } else {
            beta[(size_t)m * NH + j] = 1.f / (1.f + expf(-s));
        }
    }
}

// ---------------- causal depthwise conv(K=4) + silu + per-head l2norm (q/k) ---------
__global__ __launch_bounds__(256) void conv_qk_kernel(
    const float* __restrict__ pre, const float* __restrict__ w, float* __restrict__ out)
{
    int m = blockIdx.x;
    int b = m >> 10, t = m & 1023;
    int tid = threadIdx.x;
    int c0 = tid * 6;                 // 6 channels/thread, 8 threads per head (48 ch)
    float o[6]; float ss = 0.f;
    #pragma unroll
    for (int jj = 0; jj < 6; jj++) {
        int c = c0 + jj;
        float acc = 0.f;
        #pragma unroll
        for (int kk = 0; kk < 4; kk++) {
            int tt = t - 3 + kk;
            if (tt >= 0)
                acc += pre[((size_t)(b * TT + tt)) * KD + c] * w[c * 4 + kk];
        }
        float s = siluf(acc);
        o[jj] = s; ss += s * s;
    }
    ss += __shfl_xor(ss, 1); ss += __shfl_xor(ss, 2); ss += __shfl_xor(ss, 4);
    float rn = rsqrtf(ss + 1e-6f);
    float* orow = out + (size_t)m * KD + c0;
    #pragma unroll
    for (int jj = 0; jj < 6; jj++) orow[jj] = o[jj] * rn;
}

// ---------------- causal depthwise conv(K=4) + silu (v) ----------------
__global__ __launch_bounds__(256) void conv_v_kernel(
    const float* __restrict__ pre, const float* __restrict__ w, float* __restrict__ out)
{
    int m = blockIdx.x;
    int b = m >> 10, t = m & 1023;
    int tid = threadIdx.x;
    int c0 = tid * 12;
    float* orow = out + (size_t)m * VD + c0;
    #pragma unroll
    for (int jj = 0; jj < 12; jj++) {
        int c = c0 + jj;
        float acc = 0.f;
        #pragma unroll
        for (int kk = 0; kk < 4; kk++) {
            int tt = t - 3 + kk;
            if (tt >= 0)
                acc += pre[((size_t)(b * TT + tt)) * VD + c] * w[c * 4 + kk];
        }
        orow[jj] = siluf(acc);
    }
}

// ---------------- gated delta rule scan ----------------
#define SCH 32
__global__ __launch_bounds__(96) void scan_kernel(
    const float* __restrict__ q, const float* __restrict__ k, const float* __restrict__ v,
    const float* __restrict__ g, const float* __restrict__ beta, float* __restrict__ o)
{
    int bh = blockIdx.x;
    int b = bh >> 5, h = bh & 31;
    int tid = threadIdx.x;      // 0..95 = DV column
    __shared__ __align__(16) float ks[SCH][DKH];
    __shared__ __align__(16) float qs[SCH][DKH];
    __shared__ __align__(16) float vs[SCH][DVH];
    __shared__ float gs[SCH], bs[SCH];
    float S[DKH];
    #pragma unroll
    for (int r = 0; r < DKH; r++) S[r] = 0.f;
    const float scale = 0.14433756729740643f;   // 48^-0.5

    for (int t0 = 0; t0 < TT; t0 += SCH) {
        __syncthreads();
        for (int idx = tid; idx < SCH * DKH; idx += 96) {
            int ttc = idx / DKH, i = idx % DKH;
            size_t goff = ((size_t)(b * TT + t0 + ttc)) * KD + h * DKH + i;
            ks[ttc][i] = k[goff];
            qs[ttc][i] = q[goff];
        }
        for (int idx = tid; idx < SCH * DVH; idx += 96) {
            int ttc = idx / DVH, i = idx % DVH;
            vs[ttc][i] = v[((size_t)(b * TT + t0 + ttc)) * VD + h * DVH + i];
        }
        if (tid < SCH) {
            gs[tid] = g[(size_t)(b * TT + t0 + tid) * NH + h];
            bs[tid] = beta[(size_t)(b * TT + t0 + tid) * NH + h];
        }
        __syncthreads();

        for (int tc = 0; tc < SCH; tc++) {
            float eg = __expf(gs[tc]);
            float bt = bs[tc];
            float vt = vs[tc][tid];
            const float4* kv = (const float4*)&ks[tc][0];
            const float4* qv = (const float4*)&qs[tc][0];
            float4 kr[12];
            float m0 = 0.f, m1 = 0.f, m2 = 0.f, m3 = 0.f;
            #pragma unroll
            for (int r4 = 0; r4 < 12; r4++) {
                float4 kk4 = kv[r4];
                kr[r4] = kk4;
                S[4*r4+0] *= eg; m0 = fmaf(kk4.x, S[4*r4+0], m0);
                S[4*r4+1] *= eg; m1 = fmaf(kk4.y, S[4*r4+1], m1);
                S[4*r4+2] *= eg; m2 = fmaf(kk4.z, S[4*r4+2], m2);
                S[4*r4+3] *= eg; m3 = fmaf(kk4.w, S[4*r4+3], m3);
            }
            float delta = (vt - ((m0 + m1) + (m2 + m3))) * bt;
            float o0 = 0.f, o1 = 0.f, o2 = 0.f, o3 = 0.f;
            #pragma unroll
            for (int r4 = 0; r4 < 12; r4++) {
                float4 kk4 = kr[r4];
                float4 qq4 = qv[r4];
                S[4*r4+0] = fmaf(kk4.x, delta, S[4*r4+0]); o0 = fmaf(qq4.x, S[4*r4+0], o0);
                S[4*r4+1] = fmaf(kk4.y, delta, S[4*r4+1]); o1 = fmaf(qq4.y, S[4*r4+1], o1);
                S[4*r4+2] = fmaf(kk4.z, delta, S[4*r4+2]); o2 = fmaf(qq4.z, S[4*r4+2], o2);
                S[4*r4+3] = fmaf(kk4.w, delta, S[4*r4+3]); o3 = fmaf(qq4.w, S[4*r4+3], o3);
            }
            o[((size_t)(b * TT + t0 + tc)) * VD + h * DVH + tid] =
                ((o0 + o1) + (o2 + o3)) * scale;
        }
    }
}

// ---------------- gated per-head RMSNorm * silu(gate) -> bf16 ----------------
__global__ __launch_bounds__(256) void gatednorm_kernel(
    const float* __restrict__ oraw, const float* __restrict__ gate,
    const float* __restrict__ gw, u16* __restrict__ out)
{
    int m = blockIdx.x, tid = threadIdx.x;
    int c0 = tid * 12;                 // 8 threads per head (96 ch)
    float o[12]; float ss = 0.f;
    const float* orow = oraw + (size_t)m * VD + c0;
    #pragma unroll
    for (int jj = 0; jj < 12; jj++) { float v_ = orow[jj]; o[jj] = v_; ss += v_ * v_; }
    ss += __shfl_xor(ss, 1); ss += __shfl_xor(ss, 2); ss += __shfl_xor(ss, 4);
    float rn = rsqrtf(ss * (1.f / 96.f) + 1e-5f);
    const float* grow = gate + (size_t)m * VD + c0;
    u16* outr = out + (size_t)m * VD + c0;
    int cw0 = c0 % 96;
    #pragma unroll
    for (int jj = 0; jj < 12; jj++) {
        float gt = grow[jj];
        outr[jj] = f2bf(o[jj] * rn * gw[cw0 + jj] * siluf(gt));
    }
}

// ---------------- host launch ----------------
extern "C" void kernel_launch(void* const* d_in, const int* in_sizes, int n_in,
                              void* d_out, int out_size, void* d_ws, size_t ws_size,
                              hipStream_t stream)
{
    const float* x        = (const float*)d_in[0];
    const float* rms1_w   = (const float*)d_in[1];
    const float* rms2_w   = (const float*)d_in[2];
    const float* Wq       = (const float*)d_in[3];
    const float* Wk       = (const float*)d_in[4];
    const float* Wv       = (const float*)d_in[5];
    const float* Wa       = (const float*)d_in[6];
    const float* Wb       = (const float*)d_in[7];
    const float* Wg       = (const float*)d_in[8];
    const float* dt_bias  = (const float*)d_in[9];
    const float* A_log    = (const float*)d_in[10];
    const float* conv_q_w = (const float*)d_in[11];
    const float* conv_k_w = (const float*)d_in[12];
    const float* conv_v_w = (const float*)d_in[13];
    const float* gnorm_w  = (const float*)d_in[14];
    const float* Wo       = (const float*)d_in[15];
    const float* W1       = (const float*)d_in[16];
    const float* W3       = (const float*)d_in[17];
    const float* W2       = (const float*)d_in[18];

    float* ws = (float*)d_ws;
    const size_t M1 = 1048576;
    // arena in float units; high-water 41.75M floats = 167 MB (lifetime-checked aliases)
    u16*   wT    = (u16*)ws;                       // [0, 5.5M) — reused per weight
    u16*   h_bf  = (u16*)(ws + 11 * M1 / 2);       // [5.5, 7.5)
    float* qpre  = ws + 15 * M1 / 2;               // [7.5, 10.5)
    float* kpre  = ws + 21 * M1 / 2;               // [10.5, 13.5)
    float* vpre  = ws + 27 * M1 / 2;               // [13.5, 19.5)
    float* gate  = ws + 39 * M1 / 2;               // [19.5, 25.5)
    float* gbuf  = ws + 51 * M1 / 2;               // 64K
    float* bbuf  = gbuf + 65536;                   // 64K
    float* qb    = ws + 103 * M1 / 4;              // [25.75, 28.75)
    float* kb    = ws + 115 * M1 / 4;              // [28.75, 31.75)
    float* vb    = ws + 127 * M1 / 4;              // [31.75, 37.75)
    float* oraw  = ws + 15 * M1 / 2;               // alias qpre/kpre (dead after convs)
    u16*   o2_bf = (u16*)(ws + 27 * M1 / 2);       // alias vpre (dead after conv_v)
    float* h2    = ws + 151 * M1 / 4;              // [37.75, 41.75)
    u16*   ff_bf = (u16*)(ws + 11 * M1 / 2);       // alias h_bf (dead after Wg/proj_gb)
    float* t1    = ws + 33 * M1 / 2;               // [16.5, 27.5) alias gate/g/b/qb-head (dead)
    u16*   u_bf  = (u16*)(ws + 115 * M1 / 4);      // alias kb/vb (dead after scan)
    (void)ws_size; (void)n_in; (void)in_sizes; (void)out_size;

    // 1. h = rmsnorm(x) -> bf16
    rmsnorm_kernel<<<BT, 256, 0, stream>>>(x, rms1_w, h_bf);

    // 2. projections (transpose+cast weight, then MFMA GEMM)
    transpose_cast<<<dim3(KD/32, DMODEL/32), 256, 0, stream>>>(Wq, wT, DMODEL, KD);
    gemm_bf16<0><<<dim3(KD/128, BT/128), 256, 0, stream>>>(h_bf, wT, qpre, nullptr, BT, KD, DMODEL);
    transpose_cast<<<dim3(KD/32, DMODEL/32), 256, 0, stream>>>(Wk, wT, DMODEL, KD);
    gemm_bf16<0><<<dim3(KD/128, BT/128), 256, 0, stream>>>(h_bf, wT, kpre, nullptr, BT, KD, DMODEL);
    transpose_cast<<<dim3(VD/32, DMODEL/32), 256, 0, stream>>>(Wv, wT, DMODEL, VD);
    gemm_bf16<0><<<dim3(VD/128, BT/128), 256, 0, stream>>>(h_bf, wT, vpre, nullptr, BT, VD, DMODEL);
    transpose_cast<<<dim3(VD/32, DMODEL/32), 256, 0, stream>>>(Wg, wT, DMODEL, VD);
    gemm_bf16<0><<<dim3(VD/128, BT/128), 256, 0, stream>>>(h_bf, wT, gate, nullptr, BT, VD, DMODEL);
    proj_gb_kernel<<<BT, 256, 0, stream>>>(h_bf, Wa, Wb, dt_bias, A_log, gbuf, bbuf);

    // 3. convs (+silu, +l2norm for q/k)
    conv_qk_kernel<<<BT, 256, 0, stream>>>(qpre, conv_q_w, qb);
    conv_qk_kernel<<<BT, 256, 0, stream>>>(kpre, conv_k_w, kb);
    conv_v_kernel<<<BT, 256, 0, stream>>>(vpre, conv_v_w, vb);

    // 4. gated delta rule scan
    scan_kernel<<<BB * NH, 96, 0, stream>>>(qb, kb, vb, gbuf, bbuf, oraw);

    // 5. gated per-head rmsnorm * silu(gate) -> bf16
    gatednorm_kernel<<<BT, 256, 0, stream>>>(oraw, gate, gnorm_w, o2_bf);

    // 6. h2 = x + o2 @ Wo
    transpose_cast<<<dim3(DMODEL/32, VD/32), 256, 0, stream>>>(Wo, wT, VD, DMODEL);
    gemm_bf16<1><<<dim3(DMODEL/128, BT/128), 256, 0, stream>>>(o2_bf, wT, h2, x, BT, DMODEL, VD);

    // 7. MLP
    rmsnorm_kernel<<<BT, 256, 0, stream>>>(h2, rms2_w, ff_bf);
    transpose_cast<<<dim3(INTER/32, DMODEL/32), 256, 0, stream>>>(W1, wT, DMODEL, INTER);
    gemm_bf16<0><<<dim3(INTER/128, BT/128), 256, 0, stream>>>(ff_bf, wT, t1, nullptr, BT, INTER, DMODEL);
    transpose_cast<<<dim3(INTER/32, DMODEL/32), 256, 0, stream>>>(W3, wT, DMODEL, INTER);
    gemm_bf16<2><<<dim3(INTER/128, BT/128), 256, 0, stream>>>(ff_bf, wT, u_bf, t1, BT, INTER, DMODEL);
    transpose_cast<<<dim3(DMODEL/32, INTER/32), 256, 0, stream>>>(W2, wT, INTER, DMODEL);
    gemm_bf16<1><<<dim3(DMODEL/128, BT/128), 256, 0, stream>>>(u_bf, wT, (float*)d_out, h2, BT, DMODEL, INTER);
}

// Round 5
// 1785.916 us; speedup vs baseline: 3.2475x; 1.2223x over previous
//
#include <hip/hip_runtime.h>
#include <math.h>

// ---------------- problem constants ----------------
#define BB 2
#define TT 1024
#define DMODEL 2048
#define NH 32
#define DKH 48
#define DVH 96
#define KD 1536
#define VD 3072
#define INTER 5632
#define BT (BB*TT)

typedef unsigned short u16;
typedef __attribute__((ext_vector_type(8))) short bf16x8;
typedef __attribute__((ext_vector_type(4))) float f32x4;

__device__ __forceinline__ float siluf(float x) { return x / (1.f + __expf(-x)); }

__device__ __forceinline__ float bf2f(u16 u) {
    union { unsigned int i; float f; } v; v.i = ((unsigned int)u) << 16; return v.f;
}
__device__ __forceinline__ u16 f2bf(float f) {
    union { float f; unsigned int i; } v; v.f = f;
    unsigned int r = v.i + 0x7FFFu + ((v.i >> 16) & 1u);   // RNE
    return (u16)(r >> 16);
}

__device__ __forceinline__ void async_copy16(const void* g, void* l) {
    __builtin_amdgcn_global_load_lds(
        (const __attribute__((address_space(1))) void*)g,
        (__attribute__((address_space(3))) void*)l, 16, 0, 0);
}

// ---------------- rmsnorm (row of 2048) -> bf16 ----------------
__global__ __launch_bounds__(256) void rmsnorm_kernel(
    const float* __restrict__ x, const float* __restrict__ w, u16* __restrict__ out)
{
    int m = blockIdx.x;
    int tid = threadIdx.x;
    const float4* xr = (const float4*)(x + (size_t)m * DMODEL);
    float4 a = xr[tid];
    float4 b = xr[tid + 256];
    float ss = a.x*a.x + a.y*a.y + a.z*a.z + a.w*a.w
             + b.x*b.x + b.y*b.y + b.z*b.z + b.w*b.w;
    #pragma unroll
    for (int off = 32; off; off >>= 1) ss += __shfl_xor(ss, off);
    __shared__ float wsum[4];
    if ((tid & 63) == 0) wsum[tid >> 6] = ss;
    __syncthreads();
    float tot = wsum[0] + wsum[1] + wsum[2] + wsum[3];
    float rn = rsqrtf(tot * (1.f / DMODEL) + 1e-5f);
    const float4* wr = (const float4*)w;
    float4 w0 = wr[tid], w1 = wr[tid + 256];
    ushort4 p0, p1;
    p0.x = f2bf(a.x*rn*w0.x); p0.y = f2bf(a.y*rn*w0.y);
    p0.z = f2bf(a.z*rn*w0.z); p0.w = f2bf(a.w*rn*w0.w);
    p1.x = f2bf(b.x*rn*w1.x); p1.y = f2bf(b.y*rn*w1.y);
    p1.z = f2bf(b.z*rn*w1.z); p1.w = f2bf(b.w*rn*w1.w);
    ushort4* orow = (ushort4*)(out + (size_t)m * DMODEL);
    orow[tid] = p0; orow[tid + 256] = p1;
}

// ---------------- weight transpose + cast: in[K][N] f32 -> out[N][K] bf16 ----------------
__global__ __launch_bounds__(256) void transpose_cast(
    const float* __restrict__ in, u16* __restrict__ out, int K, int N)
{
    __shared__ float t[32][33];
    int bx = blockIdx.x;            // over N/32
    int by = blockIdx.y;            // over K/32
    int tx = threadIdx.x & 31, ty = threadIdx.x >> 5;   // ty 0..7
    #pragma unroll
    for (int r = ty; r < 32; r += 8)
        t[r][tx] = in[(size_t)(by * 32 + r) * N + bx * 32 + tx];
    __syncthreads();
    #pragma unroll
    for (int r = ty; r < 32; r += 8)
        out[(size_t)(bx * 32 + r) * K + by * 32 + tx] = f2bf(t[tx][r]);
}

// ---------------- bf16 MFMA GEMM: C[M][N] = A[M][K] @ Bt[N][K]^T  (m97 structure) ----
// MODE 0: C=f32 acc ; MODE 1: C=f32 acc + X ; MODE 2: C=bf16 silu(X)*acc
template <int MODE>
__global__ __launch_bounds__(256) void gemm_bf16(
    const u16* __restrict__ A, const u16* __restrict__ Bt,
    void* __restrict__ Cv, const float* __restrict__ X,
    int M, int N, int K)
{
    __shared__ __align__(16) u16 As[128 * 32];
    __shared__ __align__(16) u16 Bs[128 * 32];
    int tid = threadIdx.x;
    int wave = tid >> 6, lane = tid & 63;
    int wr = wave >> 1, wc = wave & 1;
    int brow = blockIdx.y * 128, bcol = blockIdx.x * 128;
    int lr = lane & 15, lg = lane >> 4;

    f32x4 acc[4][4] = {};

    int ch0 = wave * 128 + lane;        // staging chunk, call 0
    int ra0 = ch0 >> 2, pa0 = (ch0 & 3) * 8;
    int ch1 = ch0 + 64;                 // call 1
    int ra1 = ch1 >> 2, pa1 = (ch1 & 3) * 8;

    const u16* gA0 = A  + (size_t)(brow + ra0) * K + pa0;
    const u16* gA1 = A  + (size_t)(brow + ra1) * K + pa1;
    const u16* gB0 = Bt + (size_t)(bcol + ra0) * K + pa0;
    const u16* gB1 = Bt + (size_t)(bcol + ra1) * K + pa1;

    for (int kt = 0; kt < K; kt += 32) {
        __syncthreads();                          // prior reads done before overwrite
        async_copy16(gA0 + kt, &As[ch0 * 8]);
        async_copy16(gA1 + kt, &As[ch1 * 8]);
        async_copy16(gB0 + kt, &Bs[ch0 * 8]);
        async_copy16(gB1 + kt, &Bs[ch1 * 8]);
        __syncthreads();                          // compiler drains vmcnt before barrier

        bf16x8 aF[4], bF[4];
        #pragma unroll
        for (int m = 0; m < 4; m++)
            aF[m] = *(const bf16x8*)&As[(wr * 64 + m * 16 + lr) * 32 + lg * 8];
        #pragma unroll
        for (int n = 0; n < 4; n++)
            bF[n] = *(const bf16x8*)&Bs[(wc * 64 + n * 16 + lr) * 32 + lg * 8];
        #pragma unroll
        for (int m = 0; m < 4; m++)
            #pragma unroll
            for (int n = 0; n < 4; n++)
                acc[m][n] = __builtin_amdgcn_mfma_f32_16x16x32_bf16(
                    aF[m], bF[n], acc[m][n], 0, 0, 0);
    }

    // epilogue: C/D layout col=lane&15, row=(lane>>4)*4+reg  [m89-verified]
    int r0 = brow + wr * 64 + lg * 4;
    int c0 = bcol + wc * 64 + lr;
    #pragma unroll
    for (int m = 0; m < 4; m++) {
        #pragma unroll
        for (int n = 0; n < 4; n++) {
            #pragma unroll
            for (int r = 0; r < 4; r++) {
                size_t idx = (size_t)(r0 + m * 16 + r) * N + (c0 + n * 16);
                float v = acc[m][n][r];
                if (MODE == 0) {
                    ((float*)Cv)[idx] = v;
                } else if (MODE == 1) {
                    ((float*)Cv)[idx] = v + X[idx];
                } else {
                    ((u16*)Cv)[idx] = f2bf(v * siluf(X[idx]));
                }
            }
        }
    }
}

// ---------------- small projections + gating activations (Wa, Wb -> g, beta) --------
__global__ __launch_bounds__(256) void proj_gb_kernel(
    const u16* __restrict__ h, const float* __restrict__ Wa, const float* __restrict__ Wb,
    const float* __restrict__ dt_bias, const float* __restrict__ A_log,
    float* __restrict__ g, float* __restrict__ beta)
{
    int m = blockIdx.x, tid = threadIdx.x;
    __shared__ __align__(16) float hs[DMODEL];
    const uint4* hr = (const uint4*)(h + (size_t)m * DMODEL);
    uint4 hv = hr[tid];
    int base = tid * 8;
    hs[base + 0] = bf2f((u16)(hv.x & 0xffff)); hs[base + 1] = bf2f((u16)(hv.x >> 16));
    hs[base + 2] = bf2f((u16)(hv.y & 0xffff)); hs[base + 3] = bf2f((u16)(hv.y >> 16));
    hs[base + 4] = bf2f((u16)(hv.z & 0xffff)); hs[base + 5] = bf2f((u16)(hv.z >> 16));
    hs[base + 6] = bf2f((u16)(hv.w & 0xffff)); hs[base + 7] = bf2f((u16)(hv.w >> 16));
    __syncthreads();
    int out = tid >> 2;   // 0..63: 0..31 -> Wa, 32..63 -> Wb
    int part = tid & 3;
    int j = out & 31;
    const float* W = (out < 32) ? Wa : Wb;
    float s = 0.f;
    for (int kk = part; kk < DMODEL; kk += 4)
        s += hs[kk] * W[(size_t)kk * NH + j];
    s += __shfl_xor(s, 1);
    s += __shfl_xor(s, 2);
    if (part == 0) {
        if (out < 32) {
            float xx = s + dt_bias[j];
            float sp = (xx > 20.f) ? xx : log1pf(expf(xx));
            g[(size_t)m * NH + j] = -expf(A_log[j]) * sp;
        } else {
            beta[(size_t)m * NH + j] = 1.f / (1.f + expf(-s));
        }
    }
}

// ---------------- causal depthwise conv(K=4) + silu + per-head l2norm (q/k) ---------
__global__ __launch_bounds__(256) void conv_qk_kernel(
    const float* __restrict__ pre, const float* __restrict__ w, float* __restrict__ out)
{
    int m = blockIdx.x;
    int b = m >> 10, t = m & 1023;
    int tid = threadIdx.x;
    int c0 = tid * 6;                 // 6 channels/thread, 8 threads per head (48 ch)
    float o[6]; float ss = 0.f;
    #pragma unroll
    for (int jj = 0; jj < 6; jj++) {
        int c = c0 + jj;
        float acc = 0.f;
        #pragma unroll
        for (int kk = 0; kk < 4; kk++) {
            int tt = t - 3 + kk;
            if (tt >= 0)
                acc += pre[((size_t)(b * TT + tt)) * KD + c] * w[c * 4 + kk];
        }
        float s = siluf(acc);
        o[jj] = s; ss += s * s;
    }
    ss += __shfl_xor(ss, 1); ss += __shfl_xor(ss, 2); ss += __shfl_xor(ss, 4);
    float rn = rsqrtf(ss + 1e-6f);
    float* orow = out + (size_t)m * KD + c0;
    #pragma unroll
    for (int jj = 0; jj < 6; jj++) orow[jj] = o[jj] * rn;
}

// ---------------- causal depthwise conv(K=4) + silu (v) ----------------
__global__ __launch_bounds__(256) void conv_v_kernel(
    const float* __restrict__ pre, const float* __restrict__ w, float* __restrict__ out)
{
    int m = blockIdx.x;
    int b = m >> 10, t = m & 1023;
    int tid = threadIdx.x;
    int c0 = tid * 12;
    float* orow = out + (size_t)m * VD + c0;
    #pragma unroll
    for (int jj = 0; jj < 12; jj++) {
        int c = c0 + jj;
        float acc = 0.f;
        #pragma unroll
        for (int kk = 0; kk < 4; kk++) {
            int tt = t - 3 + kk;
            if (tt >= 0)
                acc += pre[((size_t)(b * TT + tt)) * VD + c] * w[c * 4 + kk];
        }
        orow[jj] = siluf(acc);
    }
}

// ---------------- gated delta rule scan (v2: 4 lanes per DV column) ----------------
// block = (b,h); 384 threads = 6 waves; lane = col*4 + dkq within wave.
// Re-associated update: mem = eg*(k.S_old); S_new = fma(k, delta, eg*S_old);
// o = q.S_new. Next step's k/q/v/eg/beta prefetched into registers.
#define SCH 32
__global__ __launch_bounds__(384) void scan_kernel(
    const float* __restrict__ q, const float* __restrict__ k, const float* __restrict__ v,
    const float* __restrict__ g, const float* __restrict__ beta, float* __restrict__ o)
{
    int bh = blockIdx.x;
    int b = bh >> 5, h = bh & 31;
    int tid = threadIdx.x;
    int lane = tid & 63;
    int wave = tid >> 6;                 // 0..5
    int col  = wave * 16 + (lane >> 2);  // 0..95 DV column
    int dkq  = lane & 3;                 // DK quarter (12 rows each)
    int r0   = dkq * 12;

    __shared__ __align__(16) float ks[SCH][DKH];
    __shared__ __align__(16) float qs[SCH][DKH];
    __shared__ __align__(16) float vs[SCH][DVH];
    __shared__ float egs[SCH], bs[SCH];

    float S[12];
    #pragma unroll
    for (int i = 0; i < 12; i++) S[i] = 0.f;
    const float scale = 0.14433756729740643f;   // 48^-0.5

    const size_t kqbase = (size_t)(b * TT) * KD + h * DKH;
    const size_t vbase  = (size_t)(b * TT) * VD + h * DVH;

    for (int t0 = 0; t0 < TT; t0 += SCH) {
        __syncthreads();
        #pragma unroll
        for (int idx = tid; idx < SCH * DKH; idx += 384) {
            int tt = idx / DKH, i = idx - tt * DKH;
            size_t goff = kqbase + (size_t)(t0 + tt) * KD + i;
            ks[tt][i] = k[goff];
            qs[tt][i] = q[goff];
        }
        #pragma unroll
        for (int idx = tid; idx < SCH * DVH; idx += 384) {
            int tt = idx / DVH, i = idx - tt * DVH;
            vs[tt][i] = v[vbase + (size_t)(t0 + tt) * VD + i];
        }
        if (tid < SCH) {
            egs[tid] = __expf(g[(size_t)(b * TT + t0 + tid) * NH + h]);
            bs[tid]  = beta[(size_t)(b * TT + t0 + tid) * NH + h];
        }
        __syncthreads();

        // preload step 0
        float4 kr[3], qr[3];
        #pragma unroll
        for (int j = 0; j < 3; j++) {
            kr[j] = *(const float4*)&ks[0][r0 + j * 4];
            qr[j] = *(const float4*)&qs[0][r0 + j * 4];
        }
        float vt = vs[0][col], eg = egs[0], bt = bs[0];

        #pragma unroll
        for (int tc = 0; tc < SCH; tc++) {
            float kk[12], qq[12];
            *(float4*)&kk[0] = kr[0]; *(float4*)&kk[4] = kr[1]; *(float4*)&kk[8] = kr[2];
            *(float4*)&qq[0] = qr[0]; *(float4*)&qq[4] = qr[1]; *(float4*)&qq[8] = qr[2];
            float ceg = eg, cbt = bt, cvt = vt;
            // prefetch next step (independent of this step's chain)
            if (tc + 1 < SCH) {
                #pragma unroll
                for (int j = 0; j < 3; j++) {
                    kr[j] = *(const float4*)&ks[tc + 1][r0 + j * 4];
                    qr[j] = *(const float4*)&qs[tc + 1][r0 + j * 4];
                }
                vt = vs[tc + 1][col]; eg = egs[tc + 1]; bt = bs[tc + 1];
            }
            // partial dot k.S_old (4 accumulators, 3-deep chains)
            float d0 = kk[0] * S[0], d1 = kk[1] * S[1], d2 = kk[2] * S[2], d3 = kk[3] * S[3];
            d0 = fmaf(kk[4], S[4], d0); d1 = fmaf(kk[5], S[5], d1);
            d2 = fmaf(kk[6], S[6], d2); d3 = fmaf(kk[7], S[7], d3);
            d0 = fmaf(kk[8], S[8], d0); d1 = fmaf(kk[9], S[9], d1);
            d2 = fmaf(kk[10], S[10], d2); d3 = fmaf(kk[11], S[11], d3);
            float dot = (d0 + d1) + (d2 + d3);
            // decayed state (parallel with dot/reduce)
            float es[12];
            #pragma unroll
            for (int i = 0; i < 12; i++) es[i] = ceg * S[i];
            // 4-lane group reduce (lanes differ in bits 0-1)
            dot += __shfl_xor(dot, 1);
            dot += __shfl_xor(dot, 2);
            float delta = (cvt - ceg * dot) * cbt;
            // rank-1 update
            #pragma unroll
            for (int i = 0; i < 12; i++) S[i] = fmaf(kk[i], delta, es[i]);
            // output dot q.S_new (off next step's critical path)
            float o0 = qq[0] * S[0], o1 = qq[1] * S[1], o2 = qq[2] * S[2], o3 = qq[3] * S[3];
            o0 = fmaf(qq[4], S[4], o0); o1 = fmaf(qq[5], S[5], o1);
            o2 = fmaf(qq[6], S[6], o2); o3 = fmaf(qq[7], S[7], o3);
            o0 = fmaf(qq[8], S[8], o0); o1 = fmaf(qq[9], S[9], o1);
            o2 = fmaf(qq[10], S[10], o2); o3 = fmaf(qq[11], S[11], o3);
            float od = (o0 + o1) + (o2 + o3);
            od += __shfl_xor(od, 1);
            od += __shfl_xor(od, 2);
            if (dkq == 0)
                o[vbase + (size_t)(t0 + tc) * VD + col] = od * scale;
        }
    }
}

// ---------------- gated per-head RMSNorm * silu(gate) -> bf16 ----------------
__global__ __launch_bounds__(256) void gatednorm_kernel(
    const float* __restrict__ oraw, const float* __restrict__ gate,
    const float* __restrict__ gw, u16* __restrict__ out)
{
    int m = blockIdx.x, tid = threadIdx.x;
    int c0 = tid * 12;                 // 8 threads per head (96 ch)
    float o[12]; float ss = 0.f;
    const float* orow = oraw + (size_t)m * VD + c0;
    #pragma unroll
    for (int jj = 0; jj < 12; jj++) { float v_ = orow[jj]; o[jj] = v_; ss += v_ * v_; }
    ss += __shfl_xor(ss, 1); ss += __shfl_xor(ss, 2); ss += __shfl_xor(ss, 4);
    float rn = rsqrtf(ss * (1.f / 96.f) + 1e-5f);
    const float* grow = gate + (size_t)m * VD + c0;
    u16* outr = out + (size_t)m * VD + c0;
    int cw0 = c0 % 96;
    #pragma unroll
    for (int jj = 0; jj < 12; jj++) {
        float gt = grow[jj];
        outr[jj] = f2bf(o[jj] * rn * gw[cw0 + jj] * siluf(gt));
    }
}

// ---------------- host launch ----------------
extern "C" void kernel_launch(void* const* d_in, const int* in_sizes, int n_in,
                              void* d_out, int out_size, void* d_ws, size_t ws_size,
                              hipStream_t stream)
{
    const float* x        = (const float*)d_in[0];
    const float* rms1_w   = (const float*)d_in[1];
    const float* rms2_w   = (const float*)d_in[2];
    const float* Wq       = (const float*)d_in[3];
    const float* Wk       = (const float*)d_in[4];
    const float* Wv       = (const float*)d_in[5];
    const float* Wa       = (const float*)d_in[6];
    const float* Wb       = (const float*)d_in[7];
    const float* Wg       = (const float*)d_in[8];
    const float* dt_bias  = (const float*)d_in[9];
    const float* A_log    = (const float*)d_in[10];
    const float* conv_q_w = (const float*)d_in[11];
    const float* conv_k_w = (const float*)d_in[12];
    const float* conv_v_w = (const float*)d_in[13];
    const float* gnorm_w  = (const float*)d_in[14];
    const float* Wo       = (const float*)d_in[15];
    const float* W1       = (const float*)d_in[16];
    const float* W3       = (const float*)d_in[17];
    const float* W2       = (const float*)d_in[18];

    float* ws = (float*)d_ws;
    const size_t M1 = 1048576;
    // arena in float units; high-water 41.75M floats = 167 MB (lifetime-checked aliases)
    u16*   wT    = (u16*)ws;                       // [0, 5.5M) — reused per weight
    u16*   h_bf  = (u16*)(ws + 11 * M1 / 2);       // [5.5, 7.5)
    float* qpre  = ws + 15 * M1 / 2;               // [7.5, 10.5)
    float* kpre  = ws + 21 * M1 / 2;               // [10.5, 13.5)
    float* vpre  = ws + 27 * M1 / 2;               // [13.5, 19.5)
    float* gate  = ws + 39 * M1 / 2;               // [19.5, 25.5)
    float* gbuf  = ws + 51 * M1 / 2;               // 64K
    float* bbuf  = gbuf + 65536;                   // 64K
    float* qb    = ws + 103 * M1 / 4;              // [25.75, 28.75)
    float* kb    = ws + 115 * M1 / 4;              // [28.75, 31.75)
    float* vb    = ws + 127 * M1 / 4;              // [31.75, 37.75)
    float* oraw  = ws + 15 * M1 / 2;               // alias qpre/kpre (dead after convs)
    u16*   o2_bf = (u16*)(ws + 27 * M1 / 2);       // alias vpre (dead after conv_v)
    float* h2    = ws + 151 * M1 / 4;              // [37.75, 41.75)
    u16*   ff_bf = (u16*)(ws + 11 * M1 / 2);       // alias h_bf (dead after Wg/proj_gb)
    float* t1    = ws + 33 * M1 / 2;               // [16.5, 27.5) alias gate/g/b/qb-head (dead)
    u16*   u_bf  = (u16*)(ws + 115 * M1 / 4);      // alias kb/vb (dead after scan)
    (void)ws_size; (void)n_in; (void)in_sizes; (void)out_size;

    // 1. h = rmsnorm(x) -> bf16
    rmsnorm_kernel<<<BT, 256, 0, stream>>>(x, rms1_w, h_bf);

    // 2. projections (transpose+cast weight, then MFMA GEMM)
    transpose_cast<<<dim3(KD/32, DMODEL/32), 256, 0, stream>>>(Wq, wT, DMODEL, KD);
    gemm_bf16<0><<<dim3(KD/128, BT/128), 256, 0, stream>>>(h_bf, wT, qpre, nullptr, BT, KD, DMODEL);
    transpose_cast<<<dim3(KD/32, DMODEL/32), 256, 0, stream>>>(Wk, wT, DMODEL, KD);
    gemm_bf16<0><<<dim3(KD/128, BT/128), 256, 0, stream>>>(h_bf, wT, kpre, nullptr, BT, KD, DMODEL);
    transpose_cast<<<dim3(VD/32, DMODEL/32), 256, 0, stream>>>(Wv, wT, DMODEL, VD);
    gemm_bf16<0><<<dim3(VD/128, BT/128), 256, 0, stream>>>(h_bf, wT, vpre, nullptr, BT, VD, DMODEL);
    transpose_cast<<<dim3(VD/32, DMODEL/32), 256, 0, stream>>>(Wg, wT, DMODEL, VD);
    gemm_bf16<0><<<dim3(VD/128, BT/128), 256, 0, stream>>>(h_bf, wT, gate, nullptr, BT, VD, DMODEL);
    proj_gb_kernel<<<BT, 256, 0, stream>>>(h_bf, Wa, Wb, dt_bias, A_log, gbuf, bbuf);

    // 3. convs (+silu, +l2norm for q/k)
    conv_qk_kernel<<<BT, 256, 0, stream>>>(qpre, conv_q_w, qb);
    conv_qk_kernel<<<BT, 256, 0, stream>>>(kpre, conv_k_w, kb);
    conv_v_kernel<<<BT, 256, 0, stream>>>(vpre, conv_v_w, vb);

    // 4. gated delta rule scan
    scan_kernel<<<BB * NH, 384, 0, stream>>>(qb, kb, vb, gbuf, bbuf, oraw);

    // 5. gated per-head rmsnorm * silu(gate) -> bf16
    gatednorm_kernel<<<BT, 256, 0, stream>>>(oraw, gate, gnorm_w, o2_bf);

    // 6. h2 = x + o2 @ Wo
    transpose_cast<<<dim3(DMODEL/32, VD/32), 256, 0, stream>>>(Wo, wT, VD, DMODEL);
    gemm_bf16<1><<<dim3(DMODEL/128, BT/128), 256, 0, stream>>>(o2_bf, wT, h2, x, BT, DMODEL, VD);

    // 7. MLP
    rmsnorm_kernel<<<BT, 256, 0, stream>>>(h2, rms2_w, ff_bf);
    transpose_cast<<<dim3(INTER/32, DMODEL/32), 256, 0, stream>>>(W1, wT, DMODEL, INTER);
    gemm_bf16<0><<<dim3(INTER/128, BT/128), 256, 0, stream>>>(ff_bf, wT, t1, nullptr, BT, INTER, DMODEL);
    transpose_cast<<<dim3(INTER/32, DMODEL/32), 256, 0, stream>>>(W3, wT, DMODEL, INTER);
    gemm_bf16<2><<<dim3(INTER/128, BT/128), 256, 0, stream>>>(ff_bf, wT, u_bf, t1, BT, INTER, DMODEL);
    transpose_cast<<<dim3(DMODEL/32, INTER/32), 256, 0, stream>>>(W2, wT, INTER, DMODEL);
    gemm_bf16<1><<<dim3(DMODEL/128, BT/128), 256, 0, stream>>>(u_bf, wT, (float*)d_out, h2, BT, DMODEL, INTER);
}